// Round 5
// baseline (61.389 us; speedup 1.0000x reference)
//
#include <hip/hip_runtime.h>

#define NCH 14
#define BT 256
#define NBLOCKS 512
#define LN2F 0.69314718055994530942f

// setup_inputs() group map: {0,1,1,2,2,0,3,3,1,2,0,3,1,2}
#define EXPECTED_PACK ((0u<<0)|(1u<<2)|(1u<<4)|(2u<<6)|(2u<<8)|(0u<<10)|(3u<<12)|(3u<<14)| \
                       (1u<<16)|(2u<<18)|(0u<<20)|(3u<<22)|(1u<<24)|(2u<<26))

__device__ __forceinline__ unsigned make_pack(const int* __restrict__ groups) {
    unsigned p = 0u;
#pragma unroll
    for (int c = 0; c < NCH; ++c) p |= ((unsigned)(groups[c] & 3)) << (2 * c);
    return p;
}

__device__ __forceinline__ void row_spec(const float* xs, const float* ts,
                                         float& accL, float& accG) {
    float lin[NCH], lg[NCH];
#pragma unroll
    for (int c = 0; c < NCH; ++c) {
        float xv = xs[c];
        lin[c] = fmaf(-xv, ts[c], fmaxf(xv, 0.0f));
        lg[c] = __log2f(1.0f + __expf(-fabsf(xv)));
    }
    // compile-time groups: g0={0,5,10} g1={1,2,8,12} g2={3,4,9,13} g3={6,7,11}
    float s1 = ts[1] + ts[2] + ts[8] + ts[12];
    float s2 = ts[3] + ts[4] + ts[9] + ts[13];
    float s3 = ts[6] + ts[7] + ts[11];

    float rL0 = lin[0] + lin[5] + lin[10],            rG0 = lg[0] + lg[5] + lg[10];
    float rL1 = lin[1] + lin[2] + lin[8] + lin[12],   rG1 = lg[1] + lg[2] + lg[8] + lg[12];
    float rL2 = lin[3] + lin[4] + lin[9] + lin[13],   rG2 = lg[3] + lg[4] + lg[9] + lg[13];
    float rL3 = lin[6] + lin[7] + lin[11],            rG3 = lg[6] + lg[7] + lg[11];

    accL += rL0;                        accG += rG0;
    accL += (s1 > 0.0f) ? rL1 : 0.0f;   accG += (s1 > 0.0f) ? rG1 : 0.0f;
    accL += (s2 > 0.0f) ? rL2 : 0.0f;   accG += (s2 > 0.0f) ? rG2 : 0.0f;
    accL += (s3 > 0.0f) ? rL3 : 0.0f;   accG += (s3 > 0.0f) ? rG3 : 0.0f;
}

__device__ __forceinline__ void row_gen(const float* xs, const float* ts,
                                        unsigned pack, float& accL, float& accG) {
    unsigned gb = 0u;
#pragma unroll
    for (int c = 0; c < NCH; ++c) {
        int gc = (pack >> (2 * c)) & 3;
        gb |= (ts[c] > 0.0f) ? (1u << gc) : 0u;
    }
#pragma unroll
    for (int c = 0; c < NCH; ++c) {
        int gc = (pack >> (2 * c)) & 3;
        float xv = xs[c];
        float lin = fmaf(-xv, ts[c], fmaxf(xv, 0.0f));
        float lg = __log2f(1.0f + __expf(-fabsf(xv)));
        bool keep = (gc == 0) || ((gb >> gc) & 1u);
        accL += keep ? lin : 0.0f;
        accG += keep ? lg : 0.0f;
    }
}

__device__ __forceinline__ void compute_pair(const float4* xv, const float4* tv,
                                             bool spec, unsigned pack,
                                             float& accL, float& accG) {
    float xs[2 * NCH], ts[2 * NCH];
#pragma unroll
    for (int j = 0; j < 7; ++j) {
        xs[4 * j + 0] = xv[j].x; xs[4 * j + 1] = xv[j].y;
        xs[4 * j + 2] = xv[j].z; xs[4 * j + 3] = xv[j].w;
        ts[4 * j + 0] = tv[j].x; ts[4 * j + 1] = tv[j].y;
        ts[4 * j + 2] = tv[j].z; ts[4 * j + 3] = tv[j].w;
    }
    if (spec) {
        row_spec(xs, ts, accL, accG);
        row_spec(xs + NCH, ts + NCH, accL, accG);
    } else {
        row_gen(xs, ts, pack, accL, accG);
        row_gen(xs + NCH, ts + NCH, pack, accL, accG);
    }
}

#define LOADP(XR, TRR, pp) do {                                        \
    const float4* xp_ = (const float4*)(x + (size_t)(pp) * (2 * NCH)); \
    const float4* tp_ = (const float4*)(t + (size_t)(pp) * (2 * NCH)); \
    _Pragma("unroll")                                                  \
    for (int j_ = 0; j_ < 7; ++j_) { XR[j_] = xp_[j_]; TRR[j_] = tp_[j_]; } \
} while (0)

__global__ __launch_bounds__(BT, 2) void bce_fused(
    const float* __restrict__ x, const float* __restrict__ t,
    const int* __restrict__ groups, float* __restrict__ partial,
    unsigned* __restrict__ counter, float* __restrict__ out,
    int rows, int iters, double inv_count)
{
    const unsigned pack = make_pack(groups);
    const bool spec = (pack == EXPECTED_PACK);
    const int pairs = rows >> 1;
    const int stride = gridDim.x * BT;

    float accL = 0.0f, accG = 0.0f;

    // A/B register double-buffer, statically named (stays in VGPRs).
    float4 xa[7], ta[7], xb[7], tb[7];
    int p = blockIdx.x * BT + threadIdx.x;
    if (p < pairs) LOADP(xa, ta, p);

    for (int it = 0; it < iters; it += 2) {
        const int p1 = p + stride;
        if ((it + 1) < iters && p1 < pairs) LOADP(xb, tb, p1);
        if (p < pairs) compute_pair(xa, ta, spec, pack, accL, accG);

        const int p2 = p1 + stride;
        if ((it + 2) < iters && p2 < pairs) LOADP(xa, ta, p2);
        if ((it + 1) < iters && p1 < pairs) compute_pair(xb, tb, spec, pack, accL, accG);

        p = p2;
    }

    // Odd-row tail (rows=2e6 -> not taken; kept for generality).
    if ((rows & 1) && blockIdx.x == 0 && threadIdx.x == 0) {
        const size_t base = (size_t)(rows - 1) * NCH;
        float xs[NCH], ts[NCH];
#pragma unroll
        for (int c = 0; c < NCH; ++c) { xs[c] = x[base + c]; ts[c] = t[base + c]; }
        row_gen(xs, ts, pack, accL, accG);
    }

    float acc = fmaf(LN2F, accG, accL);

    // 64-lane wave reduction, then block reduction.
#pragma unroll
    for (int off = 32; off > 0; off >>= 1) acc += __shfl_xor(acc, off);

    __shared__ float wsum[BT / 64];
    __shared__ bool is_last;
    const int lane = threadIdx.x & 63;
    const int wid = threadIdx.x >> 6;
    if (lane == 0) wsum[wid] = acc;
    __syncthreads();

    if (threadIdx.x == 0) {
        partial[blockIdx.x] = wsum[0] + wsum[1] + wsum[2] + wsum[3];
        __threadfence();  // make partial visible device-wide before arrival tick
        unsigned prev = atomicAdd(counter, 1u);
        is_last = (prev == gridDim.x - 1);
    }
    __syncthreads();

    // Last-arriving block reduces all partials in FIXED index order
    // (deterministic: which block runs this doesn't affect the sum).
    if (is_last) {
        __threadfence();  // acquire: observe all partial writes
        const int nb = gridDim.x;
        double s = 0.0;
        for (int i = threadIdx.x; i < nb; i += BT) s += (double)partial[i];
#pragma unroll
        for (int off = 32; off > 0; off >>= 1) s += __shfl_xor(s, off);

        __shared__ double dsum[BT / 64];
        if (lane == 0) dsum[wid] = s;
        __syncthreads();
        if (threadIdx.x == 0)
            out[0] = (float)((dsum[0] + dsum[1] + dsum[2] + dsum[3]) * inv_count);
    }
}

extern "C" void kernel_launch(void* const* d_in, const int* in_sizes, int n_in,
                              void* d_out, int out_size, void* d_ws, size_t ws_size,
                              hipStream_t stream) {
    const float* x = (const float*)d_in[0];
    const float* t = (const float*)d_in[1];
    const int* groups = (const int*)d_in[2];
    float* out = (float*)d_out;
    float* partial = (float*)d_ws;

    const int total = in_sizes[0];
    const int rows = total / NCH;
    const int pairs = rows >> 1;

    int blocks = NBLOCKS;  // persistent: 2 blocks/CU, fully resident
    const int maxb = (pairs + BT - 1) / BT;
    if (blocks > maxb) blocks = maxb;
    // need blocks floats + 4B counter in ws
    if ((size_t)(blocks + 1) * sizeof(float) > ws_size)
        blocks = (int)(ws_size / sizeof(float)) - 1;
    if (blocks < 1) blocks = 1;
    const int iters = (pairs + blocks * BT - 1) / (blocks * BT);

    unsigned* counter = (unsigned*)((char*)d_ws + (size_t)blocks * sizeof(float));
    hipMemsetAsync(counter, 0, sizeof(unsigned), stream);

    const double inv_count = 1.0 / ((double)rows * (double)NCH);
    bce_fused<<<blocks, BT, 0, stream>>>(x, t, groups, partial, counter, out,
                                         rows, iters, inv_count);
}

// Round 6
// 46.688 us; speedup vs baseline: 1.3149x; 1.3149x over previous
//
#include <hip/hip_runtime.h>

#define NCH 14
#define BT 256
#define NBLOCKS 512
#define LN2F 0.69314718055994530942f

// setup_inputs() group map: {0,1,1,2,2,0,3,3,1,2,0,3,1,2}
#define EXPECTED_PACK ((0u<<0)|(1u<<2)|(1u<<4)|(2u<<6)|(2u<<8)|(0u<<10)|(3u<<12)|(3u<<14)| \
                       (1u<<16)|(2u<<18)|(0u<<20)|(3u<<22)|(1u<<24)|(2u<<26))

__device__ __forceinline__ unsigned make_pack(const int* __restrict__ groups) {
    unsigned p = 0u;
#pragma unroll
    for (int c = 0; c < NCH; ++c) p |= ((unsigned)(groups[c] & 3)) << (2 * c);
    return p;
}

__device__ __forceinline__ void row_spec(const float* xs, const float* ts,
                                         float& accL, float& accG) {
    float lin[NCH], lg[NCH];
#pragma unroll
    for (int c = 0; c < NCH; ++c) {
        float xv = xs[c];
        lin[c] = fmaf(-xv, ts[c], fmaxf(xv, 0.0f));
        lg[c] = __log2f(1.0f + __expf(-fabsf(xv)));
    }
    // compile-time groups: g0={0,5,10} g1={1,2,8,12} g2={3,4,9,13} g3={6,7,11}
    float s1 = ts[1] + ts[2] + ts[8] + ts[12];
    float s2 = ts[3] + ts[4] + ts[9] + ts[13];
    float s3 = ts[6] + ts[7] + ts[11];

    float rL0 = lin[0] + lin[5] + lin[10],            rG0 = lg[0] + lg[5] + lg[10];
    float rL1 = lin[1] + lin[2] + lin[8] + lin[12],   rG1 = lg[1] + lg[2] + lg[8] + lg[12];
    float rL2 = lin[3] + lin[4] + lin[9] + lin[13],   rG2 = lg[3] + lg[4] + lg[9] + lg[13];
    float rL3 = lin[6] + lin[7] + lin[11],            rG3 = lg[6] + lg[7] + lg[11];

    accL += rL0;                        accG += rG0;
    accL += (s1 > 0.0f) ? rL1 : 0.0f;   accG += (s1 > 0.0f) ? rG1 : 0.0f;
    accL += (s2 > 0.0f) ? rL2 : 0.0f;   accG += (s2 > 0.0f) ? rG2 : 0.0f;
    accL += (s3 > 0.0f) ? rL3 : 0.0f;   accG += (s3 > 0.0f) ? rG3 : 0.0f;
}

__device__ __forceinline__ void row_gen(const float* xs, const float* ts,
                                        unsigned pack, float& accL, float& accG) {
    unsigned gb = 0u;
#pragma unroll
    for (int c = 0; c < NCH; ++c) {
        int gc = (pack >> (2 * c)) & 3;
        gb |= (ts[c] > 0.0f) ? (1u << gc) : 0u;
    }
#pragma unroll
    for (int c = 0; c < NCH; ++c) {
        int gc = (pack >> (2 * c)) & 3;
        float xv = xs[c];
        float lin = fmaf(-xv, ts[c], fmaxf(xv, 0.0f));
        float lg = __log2f(1.0f + __expf(-fabsf(xv)));
        bool keep = (gc == 0) || ((gb >> gc) & 1u);
        accL += keep ? lin : 0.0f;
        accG += keep ? lg : 0.0f;
    }
}

__device__ __forceinline__ void compute_pair(const float4* xv, const float4* tv,
                                             bool spec, unsigned pack,
                                             float& accL, float& accG) {
    float xs[2 * NCH], ts[2 * NCH];
#pragma unroll
    for (int j = 0; j < 7; ++j) {
        xs[4 * j + 0] = xv[j].x; xs[4 * j + 1] = xv[j].y;
        xs[4 * j + 2] = xv[j].z; xs[4 * j + 3] = xv[j].w;
        ts[4 * j + 0] = tv[j].x; ts[4 * j + 1] = tv[j].y;
        ts[4 * j + 2] = tv[j].z; ts[4 * j + 3] = tv[j].w;
    }
    if (spec) {
        row_spec(xs, ts, accL, accG);
        row_spec(xs + NCH, ts + NCH, accL, accG);
    } else {
        row_gen(xs, ts, pack, accL, accG);
        row_gen(xs + NCH, ts + NCH, pack, accL, accG);
    }
}

#define LOADP(XR, TRR, pp) do {                                        \
    const float4* xp_ = (const float4*)(x + (size_t)(pp) * (2 * NCH)); \
    const float4* tp_ = (const float4*)(t + (size_t)(pp) * (2 * NCH)); \
    _Pragma("unroll")                                                  \
    for (int j_ = 0; j_ < 7; ++j_) { XR[j_] = xp_[j_]; TRR[j_] = tp_[j_]; } \
} while (0)

__global__ __launch_bounds__(BT, 2) void bce_atomic(
    const float* __restrict__ x, const float* __restrict__ t,
    const int* __restrict__ groups, float* __restrict__ out,
    int rows, int iters, float inv_count)
{
    const unsigned pack = make_pack(groups);
    const bool spec = (pack == EXPECTED_PACK);
    const int pairs = rows >> 1;
    const int stride = gridDim.x * BT;

    float accL = 0.0f, accG = 0.0f;

    // A/B register double-buffer, statically named (stays in VGPRs).
    float4 xa[7], ta[7], xb[7], tb[7];
    int p = blockIdx.x * BT + threadIdx.x;
    if (p < pairs) LOADP(xa, ta, p);

    for (int it = 0; it < iters; it += 2) {
        const int p1 = p + stride;
        if ((it + 1) < iters && p1 < pairs) LOADP(xb, tb, p1);
        if (p < pairs) compute_pair(xa, ta, spec, pack, accL, accG);

        const int p2 = p1 + stride;
        if ((it + 2) < iters && p2 < pairs) LOADP(xa, ta, p2);
        if ((it + 1) < iters && p1 < pairs) compute_pair(xb, tb, spec, pack, accL, accG);

        p = p2;
    }

    // Odd-row tail (rows=2e6 -> not taken; kept for generality).
    if ((rows & 1) && blockIdx.x == 0 && threadIdx.x == 0) {
        const size_t base = (size_t)(rows - 1) * NCH;
        float xs[NCH], ts[NCH];
#pragma unroll
        for (int c = 0; c < NCH; ++c) { xs[c] = x[base + c]; ts[c] = t[base + c]; }
        row_gen(xs, ts, pack, accL, accG);
    }

    float acc = fmaf(LN2F, accG, accL);

    // 64-lane wave reduction, then block reduction in LDS.
#pragma unroll
    for (int off = 32; off > 0; off >>= 1) acc += __shfl_xor(acc, off);

    __shared__ float wsum[BT / 64];
    const int lane = threadIdx.x & 63;
    const int wid = threadIdx.x >> 6;
    if (lane == 0) wsum[wid] = acc;
    __syncthreads();

    // One relaxed device-scope float atomic per block (global_atomic_add_f32
    // to the coherent point; NO fence -> no buffer_wbl2 L2-writeback tail).
    // Order nondeterminism perturbs the mean at ~1e-7, far below threshold.
    if (threadIdx.x == 0) {
        float bsum = (wsum[0] + wsum[1] + wsum[2] + wsum[3]) * inv_count;
        atomicAdd(out, bsum);
    }
}

extern "C" void kernel_launch(void* const* d_in, const int* in_sizes, int n_in,
                              void* d_out, int out_size, void* d_ws, size_t ws_size,
                              hipStream_t stream) {
    const float* x = (const float*)d_in[0];
    const float* t = (const float*)d_in[1];
    const int* groups = (const int*)d_in[2];
    float* out = (float*)d_out;

    const int total = in_sizes[0];
    const int rows = total / NCH;
    const int pairs = rows >> 1;

    int blocks = NBLOCKS;  // persistent: 2 blocks/CU, fully resident
    const int maxb = (pairs + BT - 1) / BT;
    if (blocks > maxb) blocks = maxb;
    if (blocks < 1) blocks = 1;
    const int iters = (pairs + blocks * BT - 1) / (blocks * BT);

    // Zero the accumulator each call (d_out is poisoned once, not per replay).
    hipMemsetAsync(out, 0, sizeof(float), stream);

    const float inv_count = (float)(1.0 / ((double)rows * (double)NCH));
    bce_atomic<<<blocks, BT, 0, stream>>>(x, t, groups, out, rows, iters, inv_count);
}